// Round 10
// baseline (319.994 us; speedup 1.0000x reference)
//
#include <hip/hip_runtime.h>

typedef unsigned long long u64;
typedef __attribute__((ext_vector_type(4)))  int i32x4;
typedef __attribute__((ext_vector_type(16))) int i32x16;

// x [32,256,32,32] f32, w [256,256,3,3] f32; reduction R = 2304 = 36 x 64.
#define NPIX   32768
#define OCH    256
#define NCH    36

// bb_gemm geometry: 128px x 128oc block, 4 waves of 64x64, BK=64, K=36 steps.
#define AROWS  196            // px tile 128 + tap halo (+-33)
#define ALDS   (AROWS * 256)  // 50176 B dynamic LDS (A slab only; B is global->VGPR)

__device__ __forceinline__ void gload16(const void* g, void* l) {
  __builtin_amdgcn_global_load_lds(
      (const __attribute__((address_space(1))) unsigned*)g,
      (__attribute__((address_space(3))) unsigned*)l, 16, 0, 0);
}

// stage 0 (fused prep): blk 0 = zero stats + boundary masks;
// blks 1..4608 = weight sign bits WbitsT[layer][chunk][oc];
// blks 4609..9216 = i8 weight operand B3[l][tap][cb*4+s][oc][16B], where the
// original channel c = cb*64 + s*16 + j. This layout makes a wave's MFMA
// B-fragment loads two dense 512-B segments (perfectly coalesced dwordx4).
__global__ void bb_prep(const float* wa, const float* wb, u64* Wbits,
                        signed char* B, float* st, u64* masks) {
  int blk = blockIdx.x, t = threadIdx.x;
  if (blk == 0) {
    for (int i = t; i < 1024; i += 256) st[i] = 0.f;
    for (int id = t; id < 9 * NCH; id += 256) {
      int cls = id / NCH, ck = id % NCH;
      int ch = cls / 3, cw = cls % 3;
      u64 m = 0;
      for (int b = 0; b < 64; ++b) {
        int r = ck * 64 + b, tap = r % 9, kh = tap / 3, kw = tap % 3;
        bool oob = (ch == 0 && kh == 0) || (ch == 2 && kh == 2) ||
                   (cw == 0 && kw == 0) || (cw == 2 && kw == 2);
        if (!oob) m |= (u64)1 << b;
      }
      masks[id] = m;
    }
  } else if (blk <= 4608) {
    int word = (((blk - 1) << 8) + t) >> 6;
    int ln = t & 63;
    const float* src = (word < OCH * NCH) ? wa : wb;
    int r = word % (OCH * NCH);        // r = oc*36 + ck over w[o][2304]
    u64 bits = __ballot(src[(size_t)r * 64 + ln] >= 0.f);
    int l = word / (OCH * NCH);
    int o = r / NCH, ck = r % NCH;
    if (ln == 0) Wbits[(size_t)l * OCH * NCH + (size_t)ck * OCH + o] = bits;
  } else {
    int tid = ((blk - 4609) << 8) + t;  // 2 * 589824 ids
    int l = tid >= 589824;
    int r = l ? tid - 589824 : tid;
    const float* src = l ? wb : wa;
    float v = src[r];
    int tp = r % 9, oc9 = r / 9;
    int c = oc9 & 255, o = oc9 >> 8;
    int cb = c >> 6, s = (c >> 4) & 3, j = c & 15;
    B[(((size_t)((l * 9 + tp) * 16 + cb * 4 + s)) << 12) + (o << 4) + j] =
        (v >= 0.f) ? 1 : -1;
  }
}

// stage 2: x0 sign bitplanes Sb[pixel][word] + i8 NHWC operand A[px][c].
// Staged through a padded LDS transpose so the NCHW reads coalesce.
__global__ __launch_bounds__(256) void bb_xbits(const float* __restrict__ x,
                                                u64* __restrict__ Sb,
                                                signed char* __restrict__ A) {
  __shared__ float xt[256][33];
  int n = blockIdx.x >> 5, h = blockIdx.x & 31;
  int t = threadIdx.x;
  int w = t & 31, cg = t >> 5;          // 8 c-groups
  for (int k = 0; k < 32; ++k) {
    int c = k * 8 + cg;
    xt[c][w] = x[((size_t)((n * 256 + c) * 32 + h) << 5) + w];
  }
  __syncthreads();
  int ln = t & 63, wv = t >> 6;         // 4 waves = 4 channel-words
  int c2 = wv * 64 + ln;
  for (int w2 = 0; w2 < 32; ++w2) {
    bool s = xt[c2][w2] >= 0.f;
    u64 bits = __ballot(s);
    int px = (n * 32 + h) * 32 + w2;
    A[(size_t)px * 256 + c2] = s ? 1 : -1;
    if (ln == 0) Sb[(size_t)px * 4 + wv] = bits;
  }
}

// stage 3: interior conv as i8 implicit GEMM, BARRIER-FREE main loop.
// A slab [196 rows][256 c] staged once into LDS (halo covers all taps);
// B fragments load DIRECTLY global->VGPR from the L2-resident B3 layout
// (576 KB/layer, shared by all blocks). The only barrier is the prologue's
// A-handoff; the 36-step loop has no s_barrier / s_waitcnt, so the compiler
// can software-pipeline b-loads and a-reads across steps (round-9 analysis:
// the per-step barrier made each 146-cy step cost ~1900 cy).
// Boundary px compute garbage (A guards keep reads in-bounds), overwritten by
// bb_bconv. k-permutations inside fragments cancel (A,B share the mapping).
__global__ __launch_bounds__(256, 3) void bb_gemm(const signed char* __restrict__ A,
                                                  const signed char* __restrict__ B,
                                                  short* __restrict__ dst) {
  extern __shared__ signed char sm[];
  int t = threadIdx.x, wv = t >> 6, ln = t & 63;
  int lw = ln & 31, hk = ln >> 5;
  int px0 = blockIdx.x << 7;
  int oc0 = blockIdx.y << 7;

  // ---- stage A once: rows px0-33 .. px0+162 (196 rows x 256 B) ----
  const signed char* Abase = A + (size_t)(px0 - 33) * 256;
  #pragma unroll
  for (int i = 0; i < 13; ++i) {
    int c = i * 4 + wv;
    if (c < 49) {                        // 49 wave-calls x 1024 B = 50176 B
      int u = c * 64 + ln;
      int row = u >> 4, p = u & 15;
      gload16(Abase + (size_t)row * 256 + (((p ^ (row & 7)) << 4)),
              &sm[c * 1024]);
    }
  }
  asm volatile("s_waitcnt vmcnt(0)" ::: "memory");
  __builtin_amdgcn_s_barrier();

  int wm = wv >> 1, wn = wv & 1;
  int arow0 = 33 + (wm << 6) + lw;
  // B fragment base for this lane: row = oc0 + wn*64 + lw, k-half = hk.
  const signed char* Bw = B + (((size_t)(oc0 + (wn << 6) + lw)) << 4);
  i32x16 acc00 = {0,0,0,0,0,0,0,0,0,0,0,0,0,0,0,0};
  i32x16 acc01 = acc00, acc10 = acc00, acc11 = acc00;

  #pragma unroll 4
  for (int ks = 0; ks < 36; ++ks) {
    int tp = ks >> 2, cb = ks & 3;
    int dpx = (tp / 3 - 1) * 32 + (tp % 3 - 1);
    int r0 = arow0 + dpx, r1 = r0 + 32;
    #pragma unroll
    for (int k32 = 0; k32 < 2; ++k32) {
      int sa = cb * 4 + k32 * 2 + hk;
      size_t bb = ((size_t)(tp * 16 + cb * 4 + k32 * 2 + hk)) << 12;
      i32x4 a0 = *(const i32x4*)(sm + r0 * 256 + ((sa ^ (r0 & 7)) << 4));
      i32x4 a1 = *(const i32x4*)(sm + r1 * 256 + ((sa ^ (r1 & 7)) << 4));
      i32x4 b0 = *(const i32x4*)(Bw + bb);
      i32x4 b1 = *(const i32x4*)(Bw + bb + (32 << 4));
      acc00 = __builtin_amdgcn_mfma_i32_32x32x32_i8(a0, b0, acc00, 0, 0, 0);
      acc01 = __builtin_amdgcn_mfma_i32_32x32x32_i8(a0, b1, acc01, 0, 0, 0);
      acc10 = __builtin_amdgcn_mfma_i32_32x32x32_i8(a1, b0, acc10, 0, 0, 0);
      acc11 = __builtin_amdgcn_mfma_i32_32x32x32_i8(a1, b1, acc11, 0, 0, 0);
    }
  }

  int px0w = px0 + (wm << 6), oc0w = oc0 + (wn << 6);
  int rbase = hk << 2;
  #pragma unroll
  for (int r = 0; r < 16; ++r) {       // C/D: col=lane&31, row=(r&3)+8*(r>>2)+4*hk
    int m = (r & 3) + ((r >> 2) << 3) + rbase;
    size_t row0 = ((size_t)(px0w + m)) << 8;
    size_t row1 = ((size_t)(px0w + 32 + m)) << 8;
    int v;
    v = acc00[r]; v = v < -254 ? -254 : (v > 254 ? 254 : v);
    dst[row0 + oc0w + lw] = (short)v;
    v = acc01[r]; v = v < -254 ? -254 : (v > 254 ? 254 : v);
    dst[row0 + oc0w + 32 + lw] = (short)v;
    v = acc10[r]; v = v < -254 ? -254 : (v > 254 ? 254 : v);
    dst[row1 + oc0w + lw] = (short)v;
    v = acc11[r]; v = v < -254 ? -254 : (v > 254 ? 254 : v);
    dst[row1 + oc0w + 32 + lw] = (short)v;
  }
}

// stage 4: boundary pixels, 16 px per block (248 blocks), exact masked path.
__global__ __launch_bounds__(256) void bb_bconv(const u64* __restrict__ Sb,
                                                const u64* __restrict__ Wb,
                                                const u64* __restrict__ masks,
                                                short* __restrict__ dst) {
  __shared__ u64 spread[256];
  __shared__ u64 pw[16][NCH];
  __shared__ u64 mm[16][NCH];
  __shared__ int pm[16][NCH];
  __shared__ int pxl[16];
  int t = threadIdx.x;
  {
    u64 v = 0;
    for (int k = 0; k < 8; ++k) if (t & (1 << k)) v |= (u64)1 << (9 * k);
    spread[t] = v;
  }
  __syncthreads();
  for (int id = t; id < 16 * NCH; id += 256) {
    int p = id / NCH, ck = id % NCH;
    int gp = blockIdx.x * 16 + p;
    int n = gp / 124, r = gp % 124;
    int h, w;
    if (r < 32)      { h = 0;      w = r;      }
    else if (r < 64) { h = 31;     w = r - 32; }
    else if (r < 94) { h = r - 63; w = 0;      }
    else             { h = r - 93; w = 31;     }
    int cls = (h == 0 ? 0 : (h == 31 ? 2 : 1)) * 3 + (w == 0 ? 0 : (w == 31 ? 2 : 1));
    if (ck == 0) pxl[p] = ((n * 32 + h) << 5) + w;
    int base9 = ck % 9;
    u64 acc = 0;
    for (int tap = 0; tap < 9; ++tap) {
      int b0 = tap - base9; if (b0 < 0) b0 += 9;
      int nh = h + tap / 3 - 1, nw = w + tap % 3 - 1;
      if ((unsigned)nh <= 31u && (unsigned)nw <= 31u) {
        int run = (b0 == 0) ? 8 : 7;
        int c0 = (ck * 64 + b0) / 9;
        const u64* rp = Sb + ((size_t)((n * 32 + nh) * 32 + nw) << 2);
        int wi = c0 >> 6, sh = c0 & 63;
        u64 v = rp[wi] >> sh;
        if (sh + run > 64) v |= rp[wi + 1] << (64 - sh);
        v &= (run == 8) ? 0xFFull : 0x7Full;
        acc |= spread[(int)v] << b0;
      }
    }
    pw[p][ck] = acc;
    u64 m = masks[cls * NCH + ck];
    mm[p][ck] = m;
    pm[p][ck] = __popcll(m);
  }
  __syncthreads();
  int oc = t;
  int acc[16];
  #pragma unroll
  for (int p = 0; p < 16; ++p) acc[p] = 0;
  for (int i = 0; i < NCH; ++i) {
    u64 wr = Wb[(size_t)i * OCH + oc];
    #pragma unroll
    for (int p = 0; p < 16; ++p) {
      int d = __popcll((pw[p][i] ^ wr) & mm[p][i]);
      int ps = pm[p][i] - 2 * d;
      acc[p] += ps + (ps & 1) * ((ps & 2) - 1);
    }
  }
  #pragma unroll
  for (int p = 0; p < 16; ++p) {
    int v = acc[p];
    v = v < -254 ? -254 : (v > 254 ? 254 : v);
    dst[(size_t)pxl[p] * OCH + oc] = (short)v;
  }
}

// stage 5: BN1 batch stats (integer values -> exact f32 sums).
__global__ void bb_stats1(const short* v16, float* st) {
  int t = threadIdx.x;
  const short* base = v16 + (size_t)blockIdx.x * 128 * OCH;
  int s = 0; float q = 0.f;
  for (int r = 0; r < 128; ++r) {
    int v = base[r * OCH + t];
    s += v; q += (float)(v * v);
  }
  atomicAdd(&st[t], (float)s);
  atomicAdd(&st[256 + t], q);
}

// stage 6: BN1 + hardtanh + sign-pack (hardtanh preserves sign) + i8 NHWC A2.
__global__ void bb_xbits2(const short* v16, const float* st,
                          const float* g, const float* b, u64* Sb,
                          signed char* A) {
  int wave = (blockIdx.x * blockDim.x + threadIdx.x) >> 6;
  int ln = threadIdx.x & 63;
  int wrd = wave & 3, px0 = (wave >> 2) * 32;
  int oc = wrd * 64 + ln;
  float mu = st[oc] * (1.f / 32768.f);
  float va = st[256 + oc] * (1.f / 32768.f) - mu * mu;
  float rs = rsqrtf(va + 1e-5f);
  float gg = g[oc], bb = b[oc];
  for (int j = 0; j < 32; ++j) {
    float bn = ((float)v16[(size_t)(px0 + j) * OCH + oc] - mu) * rs * gg + bb;
    bool s = bn >= 0.f;
    u64 bits = __ballot(s);
    A[(size_t)(px0 + j) * 256 + oc] = s ? 1 : -1;
    if (ln == 0) Sb[(size_t)(px0 + j) * 4 + wrd] = bits;
  }
}

// stage 7: BN2 batch stats of (conv2 + residual). Block = one (n,h) row-tile.
__global__ __launch_bounds__(256) void bb_stats2t(const short* __restrict__ pre16,
                                                  const float* __restrict__ x0,
                                                  float* st) {
  __shared__ float xt[32][257];
  int blk = blockIdx.x;                 // blk = n*32 + h
  int n = blk >> 5, h = blk & 31;
  int t = threadIdx.x;
  int w = t & 31, og = t >> 5;          // 8 oc-groups
  for (int k = 0; k < 32; ++k) {
    int oc = og * 32 + k;
    xt[w][oc] = x0[((size_t)(n * 256 + oc) * 32 + h) * 32 + w];
  }
  __syncthreads();
  int oc = t;
  size_t pb = (size_t)blk * 32 * OCH + oc;
  float s = 0.f, q = 0.f;
  for (int w2 = 0; w2 < 32; ++w2) {
    float v = (float)pre16[pb + (size_t)w2 * OCH] + xt[w2][oc];
    s += v; q += v * v;
  }
  atomicAdd(&st[512 + oc], s);
  atomicAdd(&st[768 + oc], q);
}

// stage 8: BN2 + hardtanh + NCHW store via in-place LDS transpose;
// reg output is data-independent: reg = reg0 + r1 + 2*r2 = reg0 + 8.625.
__global__ __launch_bounds__(256) void bb_fint(const short* __restrict__ pre16,
                                               const float* __restrict__ x0,
                                               const float* st, const float* g,
                                               const float* b, const float* r0,
                                               float* __restrict__ out) {
  __shared__ float xt[32][257];
  int blk = blockIdx.x;
  int n = blk >> 5, h = blk & 31;
  int t = threadIdx.x;
  int w = t & 31, og = t >> 5;
  for (int k = 0; k < 32; ++k) {
    int oc = og * 32 + k;
    xt[w][oc] = x0[((size_t)(n * 256 + oc) * 32 + h) * 32 + w];
  }
  __syncthreads();
  int oc = t;
  float mu = st[512 + oc] * (1.f / 32768.f);
  float va = st[768 + oc] * (1.f / 32768.f) - mu * mu;
  float rs = rsqrtf(va + 1e-5f);
  float gg = g[oc], bb = b[oc];
  size_t pb = (size_t)blk * 32 * OCH + oc;
  for (int w2 = 0; w2 < 32; ++w2) {
    float v = (float)pre16[pb + (size_t)w2 * OCH] + xt[w2][oc];
    v = (v - mu) * rs * gg + bb;
    xt[w2][oc] = fminf(fmaxf(v, -1.f), 1.f);   // in-place: col oc owned by thread
  }
  __syncthreads();
  for (int k = 0; k < 32; ++k) {
    int oc2 = og * 32 + k;
    out[((size_t)(n * 256 + oc2) * 32 + h) * 32 + w] = xt[w][oc2];
  }
  if (blk == 0 && t == 0) out[8388608] = r0[0] + 8.625f;
}

extern "C" void kernel_launch(void* const* d_in, const int* in_sizes, int n_in,
                              void* d_out, int out_size, void* d_ws, size_t ws_size,
                              hipStream_t stream) {
  const float* x0   = (const float*)d_in[0];
  const float* reg0 = (const float*)d_in[1];
  const float* w1   = (const float*)d_in[2];
  const float* g1   = (const float*)d_in[3];
  const float* b1   = (const float*)d_in[4];
  const float* w2   = (const float*)d_in[5];
  const float* g2   = (const float*)d_in[6];
  const float* b2   = (const float*)d_in[7];

  char* ws = (char*)d_ws;
  u64*   Wbits = (u64*)(ws);                        // 147456 B  [layer][ck][oc]
  u64*   masks = (u64*)(ws + 147456);               // 2592 B
  float* st    = (float*)(ws + 151552);             // 4 KiB
  u64*   Sb    = (u64*)(ws + 155648);               // 1 MiB
  signed char* Bi8 = (signed char*)(ws + 1204224);  // 1179648 B  B3 layout
  signed char* Ai8 = (signed char*)(ws + 2383872) + 32768;  // 8 MiB + 32K guards
  short* v16   = (short*)(ws + 10838016);           // 16 MiB (conv1 out,
                                                    //  then reused for conv2)

  bb_prep   <<<9217, 256, 0, stream>>>(w1, w2, Wbits, Bi8, st, masks);
  bb_xbits  <<<1024, 256, 0, stream>>>(x0, Sb, Ai8);
  bb_gemm   <<<dim3(256, 2), 256, ALDS, stream>>>(Ai8, Bi8, v16);
  bb_bconv  <<<248,  256, 0, stream>>>(Sb, Wbits, masks, v16);
  bb_stats1 <<<256,  256, 0, stream>>>(v16, st);
  bb_xbits2 <<<1024, 256, 0, stream>>>(v16, st, g1, b1, Sb, Ai8);
  bb_gemm   <<<dim3(256, 2), 256, ALDS, stream>>>(Ai8, Bi8 + 589824, v16);
  bb_bconv  <<<248,  256, 0, stream>>>(Sb, Wbits + OCH * NCH, masks, v16);
  bb_stats2t<<<1024, 256, 0, stream>>>(v16, x0, st);
  bb_fint   <<<1024, 256, 0, stream>>>(v16, x0, st, g2, b2, reg0, (float*)d_out);
}

// Round 12
// 283.437 us; speedup vs baseline: 1.1290x; 1.1290x over previous
//
#include <hip/hip_runtime.h>

typedef unsigned long long u64;
typedef __attribute__((ext_vector_type(4)))  int i32x4;
typedef __attribute__((ext_vector_type(16))) int i32x16;

// x [32,256,32,32] f32, w [256,256,3,3] f32; reduction R = 2304 = 36 x 64.
#define NPIX   32768
#define OCH    256
#define NCH    36

// gemm geometry: 128px x 128oc block, 4 waves of 64x64, BK=64, K=36 steps.
#define AROWS  196            // px tile 128 + tap halo (+-33)
#define ALDS   (AROWS * 256)  // 50176 B, staged ONCE per block (all taps, all K)
#define BLDS   8192           // 128 oc x 64 c, TRIPLE-buffered (counted vmcnt)
#define GLDS   (ALDS + 3 * BLDS)   // 74752 B dynamic LDS -> 2 blocks/CU

__device__ __forceinline__ void gload16(const void* g, void* l) {
  __builtin_amdgcn_global_load_lds(
      (const __attribute__((address_space(1))) unsigned*)g,
      (__attribute__((address_space(3))) unsigned*)l, 16, 0, 0);
}

// stage 0 (mega-prep, 10241 blocks): all four independent prep passes in one
// dispatch so their latency overlaps on idle CUs.
//   blk 0                : zero stats + boundary masks
//   blk 1..4608          : weight sign bits WbitsT[layer][chunk][oc]
//   blk 4609..9216       : i8 weight operand B'[l][tap][oc][c]
//   blk 9217..10240      : x0 sign bitplanes Sb + i8 NHWC operand A
__global__ __launch_bounds__(256) void bb_pre(const float* __restrict__ wa,
                                              const float* __restrict__ wb,
                                              const float* __restrict__ x,
                                              u64* __restrict__ Wbits,
                                              signed char* __restrict__ B,
                                              float* __restrict__ st,
                                              u64* __restrict__ masks,
                                              u64* __restrict__ Sb,
                                              signed char* __restrict__ A) {
  __shared__ float xt[256][33];
  int blk = blockIdx.x, t = threadIdx.x;
  if (blk == 0) {
    for (int i = t; i < 1024; i += 256) st[i] = 0.f;
    for (int id = t; id < 9 * NCH; id += 256) {
      int cls = id / NCH, ck = id % NCH;
      int ch = cls / 3, cw = cls % 3;
      u64 m = 0;
      for (int b = 0; b < 64; ++b) {
        int r = ck * 64 + b, tap = r % 9, kh = tap / 3, kw = tap % 3;
        bool oob = (ch == 0 && kh == 0) || (ch == 2 && kh == 2) ||
                   (cw == 0 && kw == 0) || (cw == 2 && kw == 2);
        if (!oob) m |= (u64)1 << b;
      }
      masks[id] = m;
    }
  } else if (blk <= 4608) {
    int word = (((blk - 1) << 8) + t) >> 6;
    int ln = t & 63;
    const float* src = (word < OCH * NCH) ? wa : wb;
    int r = word % (OCH * NCH);        // r = oc*36 + ck over w[o][2304]
    u64 bits = __ballot(src[(size_t)r * 64 + ln] >= 0.f);
    int l = word / (OCH * NCH);
    int o = r / NCH, ck = r % NCH;
    if (ln == 0) Wbits[(size_t)l * OCH * NCH + (size_t)ck * OCH + o] = bits;
  } else if (blk <= 9216) {
    int tid = ((blk - 4609) << 8) + t;  // 2 * 589824 ids
    int l = tid >= 589824;
    int r = l ? tid - 589824 : tid;
    const float* src = l ? wb : wa;
    float v = src[r];
    int tp = r % 9, oc9 = r / 9;
    int c = oc9 & 255, o = oc9 >> 8;
    B[(((size_t)(l * 9 + tp) * 256 + o) << 8) + c] = (v >= 0.f) ? 1 : -1;
  } else {
    int bx = blk - 9217;               // 1024 xbits blocks
    int n = bx >> 5, h = bx & 31;
    int w = t & 31, cg = t >> 5;        // 8 c-groups
    for (int k = 0; k < 32; ++k) {
      int c = k * 8 + cg;
      xt[c][w] = x[((size_t)((n * 256 + c) * 32 + h) << 5) + w];
    }
    __syncthreads();
    int ln = t & 63, wv = t >> 6;       // 4 waves = 4 channel-words
    int c2 = wv * 64 + ln;
    for (int w2 = 0; w2 < 32; ++w2) {
      bool s = xt[c2][w2] >= 0.f;
      u64 bits = __ballot(s);
      int px = (n * 32 + h) * 32 + w2;
      A[(size_t)px * 256 + c2] = s ? 1 : -1;
      if (ln == 0) Sb[(size_t)px * 4 + wv] = bits;
    }
  }
}

// stage 1 (merged conv, 760 blocks, dynamic LDS = GLDS):
//   bx 0..511   : interior i8 implicit GEMM (round-5 structure). Epilogue
//                 stores are MASKED to interior pixels only (h,w in [1,30]) --
//                 round-11 lesson: in a merged dispatch the old
//                 write-garbage-then-overwrite scheme races with the bconv
//                 blocks; masking makes the write sets disjoint.
//   bx 512..759 : boundary pixels, 16 px per block, exact masked path; LDS
//                 carved from the same dynamic buffer.
__global__ __launch_bounds__(256, 2) void bb_conv(const signed char* __restrict__ A,
                                                  const signed char* __restrict__ B,
                                                  const u64* __restrict__ Sb,
                                                  const u64* __restrict__ Wb,
                                                  const u64* __restrict__ masks,
                                                  short* __restrict__ dst) {
  extern __shared__ signed char sm[];
  int bx = blockIdx.x, t = threadIdx.x;
  if (bx < 512) {
    int wv = t >> 6, ln = t & 63;
    int lw = ln & 31, hk = ln >> 5;
    int px0 = (bx >> 1) << 7;
    int oc0 = (bx & 1) << 7;

    // ---- stage A once: rows px0-33 .. px0+162 (196 rows x 256 B) ----
    const signed char* Abase = A + (size_t)(px0 - 33) * 256;
    #pragma unroll
    for (int i = 0; i < 13; ++i) {
      int c = i * 4 + wv;
      if (c < 49) {
        int u = c * 64 + ln;
        int row = u >> 4, p = u & 15;
        gload16(Abase + (size_t)row * 256 + (((p ^ (row & 7)) << 4)),
                &sm[c * 1024]);
      }
    }

    #define STAGE_B(bufi, ks) do {                                            \
      int tp_ = (ks) >> 2, cb_ = (ks) & 3;                                    \
      const signed char* Bb_ = B + ((size_t)tp_ << 16) + (size_t)oc0 * 256    \
                                 + (cb_ << 6);                                \
      _Pragma("unroll")                                                       \
      for (int i_ = 0; i_ < 2; ++i_) {                                        \
        int c_ = wv * 2 + i_;                                                 \
        int u_ = c_ * 64 + ln;                                                \
        int row_ = u_ >> 2, p_ = u_ & 3;                                      \
        gload16(Bb_ + (size_t)row_ * 256 + (((p_ ^ ((row_ >> 1) & 3)) << 4)), \
                &sm[ALDS + (bufi) * BLDS + c_ * 1024]);                       \
      }                                                                       \
    } while (0)

    STAGE_B(0, 0);
    STAGE_B(1, 1);
    asm volatile("s_waitcnt vmcnt(2)" ::: "memory");
    __builtin_amdgcn_s_barrier();

    int wm = wv >> 1, wn = wv & 1;
    int arow0 = 33 + (wm << 6) + lw;
    int brow0 = (wn << 6) + lw;
    i32x16 acc00 = {0,0,0,0,0,0,0,0,0,0,0,0,0,0,0,0};
    i32x16 acc01 = acc00, acc10 = acc00, acc11 = acc00;

    for (int ks = 0; ks < 36; ++ks) {
      if (ks + 2 < 36) STAGE_B((ks + 2) % 3, ks + 2);
      int tp = ks >> 2, cb = ks & 3;
      int dpx = (tp / 3 - 1) * 32 + (tp % 3 - 1);
      int r0 = arow0 + dpx, r1 = r0 + 32;
      int q0 = brow0, q1 = brow0 + 32;
      const signed char* Bl = sm + ALDS + (ks % 3) * BLDS;
      __builtin_amdgcn_s_setprio(1);
      #pragma unroll
      for (int k32 = 0; k32 < 2; ++k32) {
        int sa = cb * 4 + k32 * 2 + hk;
        int sb = k32 * 2 + hk;
        i32x4 a0 = *(const i32x4*)(sm + r0 * 256 + ((sa ^ (r0 & 7)) << 4));
        i32x4 a1 = *(const i32x4*)(sm + r1 * 256 + ((sa ^ (r1 & 7)) << 4));
        i32x4 b0 = *(const i32x4*)(Bl + q0 * 64 + ((sb ^ ((q0 >> 1) & 3)) << 4));
        i32x4 b1 = *(const i32x4*)(Bl + q1 * 64 + ((sb ^ ((q1 >> 1) & 3)) << 4));
        acc00 = __builtin_amdgcn_mfma_i32_32x32x32_i8(a0, b0, acc00, 0, 0, 0);
        acc01 = __builtin_amdgcn_mfma_i32_32x32x32_i8(a0, b1, acc01, 0, 0, 0);
        acc10 = __builtin_amdgcn_mfma_i32_32x32x32_i8(a1, b0, acc10, 0, 0, 0);
        acc11 = __builtin_amdgcn_mfma_i32_32x32x32_i8(a1, b1, acc11, 0, 0, 0);
      }
      __builtin_amdgcn_s_setprio(0);
      if (ks < 34) asm volatile("s_waitcnt vmcnt(2)" ::: "memory");
      else         asm volatile("s_waitcnt vmcnt(0)" ::: "memory");
      __builtin_amdgcn_s_barrier();
    }
    #undef STAGE_B

    int px0w = px0 + (wm << 6), oc0w = oc0 + (wn << 6);
    int rbase = hk << 2;
    int h0 = (px0w >> 5) & 31, h1 = ((px0w + 32) >> 5) & 31;
    bool i0 = (h0 >= 1) && (h0 <= 30);
    bool i1 = (h1 >= 1) && (h1 <= 30);
    #pragma unroll
    for (int r = 0; r < 16; ++r) {     // C/D: col=lane&31, row=(r&3)+8*(r>>2)+4*hk
      int m = (r & 3) + ((r >> 2) << 3) + rbase;
      bool wok = (m >= 1) && (m <= 30);
      size_t row0 = ((size_t)(px0w + m)) << 8;
      size_t row1 = ((size_t)(px0w + 32 + m)) << 8;
      int v;
      if (i0 && wok) {
        v = acc00[r]; v = v < -254 ? -254 : (v > 254 ? 254 : v);
        dst[row0 + oc0w + lw] = (short)v;
        v = acc01[r]; v = v < -254 ? -254 : (v > 254 ? 254 : v);
        dst[row0 + oc0w + 32 + lw] = (short)v;
      }
      if (i1 && wok) {
        v = acc10[r]; v = v < -254 ? -254 : (v > 254 ? 254 : v);
        dst[row1 + oc0w + lw] = (short)v;
        v = acc11[r]; v = v < -254 ? -254 : (v > 254 ? 254 : v);
        dst[row1 + oc0w + 32 + lw] = (short)v;
      }
    }
    return;
  }

  // ---- boundary path: LDS carved from the dynamic buffer ----
  u64* spread = (u64*)sm;                    // 2048 B
  u64* pw     = spread + 256;                // 16*36 u64 = 4608 B
  u64* mm     = pw + 16 * NCH;               // 4608 B
  int* pm     = (int*)(mm + 16 * NCH);       // 2304 B
  int* pxl    = pm + 16 * NCH;               // 64 B   (total ~13.6 KB < GLDS)
  {
    u64 v = 0;
    for (int k = 0; k < 8; ++k) if (t & (1 << k)) v |= (u64)1 << (9 * k);
    spread[t] = v;
  }
  __syncthreads();
  int bb = bx - 512;
  for (int id = t; id < 16 * NCH; id += 256) {
    int p = id / NCH, ck = id % NCH;
    int gp = bb * 16 + p;
    int n = gp / 124, r = gp % 124;
    int h, w;
    if (r < 32)      { h = 0;      w = r;      }
    else if (r < 64) { h = 31;     w = r - 32; }
    else if (r < 94) { h = r - 63; w = 0;      }
    else             { h = r - 93; w = 31;     }
    int cls = (h == 0 ? 0 : (h == 31 ? 2 : 1)) * 3 + (w == 0 ? 0 : (w == 31 ? 2 : 1));
    if (ck == 0) pxl[p] = ((n * 32 + h) << 5) + w;
    int base9 = ck % 9;
    u64 acc = 0;
    for (int tap = 0; tap < 9; ++tap) {
      int b0 = tap - base9; if (b0 < 0) b0 += 9;
      int nh = h + tap / 3 - 1, nw = w + tap % 3 - 1;
      if ((unsigned)nh <= 31u && (unsigned)nw <= 31u) {
        int run = (b0 == 0) ? 8 : 7;
        int c0 = (ck * 64 + b0) / 9;
        const u64* rp = Sb + ((size_t)((n * 32 + nh) * 32 + nw) << 2);
        int wi = c0 >> 6, sh = c0 & 63;
        u64 v = rp[wi] >> sh;
        if (sh + run > 64) v |= rp[wi + 1] << (64 - sh);
        v &= (run == 8) ? 0xFFull : 0x7Full;
        acc |= spread[(int)v] << b0;
      }
    }
    pw[p * NCH + ck] = acc;
    u64 m = masks[cls * NCH + ck];
    mm[p * NCH + ck] = m;
    pm[p * NCH + ck] = __popcll(m);
  }
  __syncthreads();
  int oc = t;
  int acc[16];
  #pragma unroll
  for (int p = 0; p < 16; ++p) acc[p] = 0;
  for (int i = 0; i < NCH; ++i) {
    u64 wr = Wb[(size_t)i * OCH + oc];
    #pragma unroll
    for (int p = 0; p < 16; ++p) {
      int d = __popcll((pw[p * NCH + i] ^ wr) & mm[p * NCH + i]);
      int ps = pm[p * NCH + i] - 2 * d;
      acc[p] += ps + (ps & 1) * ((ps & 2) - 1);
    }
  }
  #pragma unroll
  for (int p = 0; p < 16; ++p) {
    int v = acc[p];
    v = v < -254 ? -254 : (v > 254 ? 254 : v);
    dst[(size_t)pxl[p] * OCH + oc] = (short)v;
  }
}

// stage 2: BN1 batch stats (integer values -> exact f32 sums).
__global__ void bb_stats1(const short* v16, float* st) {
  int t = threadIdx.x;
  const short* base = v16 + (size_t)blockIdx.x * 128 * OCH;
  int s = 0; float q = 0.f;
  for (int r = 0; r < 128; ++r) {
    int v = base[r * OCH + t];
    s += v; q += (float)(v * v);
  }
  atomicAdd(&st[t], (float)s);
  atomicAdd(&st[256 + t], q);
}

// stage 3: BN1 + hardtanh + sign-pack (hardtanh preserves sign) + i8 NHWC A2.
__global__ void bb_xbits2(const short* v16, const float* st,
                          const float* g, const float* b, u64* Sb,
                          signed char* A) {
  int wave = (blockIdx.x * blockDim.x + threadIdx.x) >> 6;
  int ln = threadIdx.x & 63;
  int wrd = wave & 3, px0 = (wave >> 2) * 32;
  int oc = wrd * 64 + ln;
  float mu = st[oc] * (1.f / 32768.f);
  float va = st[256 + oc] * (1.f / 32768.f) - mu * mu;
  float rs = rsqrtf(va + 1e-5f);
  float gg = g[oc], bb = b[oc];
  for (int j = 0; j < 32; ++j) {
    float bn = ((float)v16[(size_t)(px0 + j) * OCH + oc] - mu) * rs * gg + bb;
    bool s = bn >= 0.f;
    u64 bits = __ballot(s);
    A[(size_t)(px0 + j) * 256 + oc] = s ? 1 : -1;
    if (ln == 0) Sb[(size_t)(px0 + j) * 4 + wrd] = bits;
  }
}

// stage 4: BN2 batch stats of (conv2 + residual). Block = one (n,h) row-tile.
__global__ __launch_bounds__(256) void bb_stats2t(const short* __restrict__ pre16,
                                                  const float* __restrict__ x0,
                                                  float* st) {
  __shared__ float xt[32][257];
  int blk = blockIdx.x;                 // blk = n*32 + h
  int n = blk >> 5, h = blk & 31;
  int t = threadIdx.x;
  int w = t & 31, og = t >> 5;          // 8 oc-groups
  for (int k = 0; k < 32; ++k) {
    int oc = og * 32 + k;
    xt[w][oc] = x0[((size_t)(n * 256 + oc) * 32 + h) * 32 + w];
  }
  __syncthreads();
  int oc = t;
  size_t pb = (size_t)blk * 32 * OCH + oc;
  float s = 0.f, q = 0.f;
  for (int w2 = 0; w2 < 32; ++w2) {
    float v = (float)pre16[pb + (size_t)w2 * OCH] + xt[w2][oc];
    s += v; q += v * v;
  }
  atomicAdd(&st[512 + oc], s);
  atomicAdd(&st[768 + oc], q);
}

// stage 5: BN2 + hardtanh + NCHW store via in-place LDS transpose;
// reg output is data-independent: reg = reg0 + r1 + 2*r2 = reg0 + 8.625.
__global__ __launch_bounds__(256) void bb_fint(const short* __restrict__ pre16,
                                               const float* __restrict__ x0,
                                               const float* st, const float* g,
                                               const float* b, const float* r0,
                                               float* __restrict__ out) {
  __shared__ float xt[32][257];
  int blk = blockIdx.x;
  int n = blk >> 5, h = blk & 31;
  int t = threadIdx.x;
  int w = t & 31, og = t >> 5;
  for (int k = 0; k < 32; ++k) {
    int oc = og * 32 + k;
    xt[w][oc] = x0[((size_t)(n * 256 + oc) * 32 + h) * 32 + w];
  }
  __syncthreads();
  int oc = t;
  float mu = st[512 + oc] * (1.f / 32768.f);
  float va = st[768 + oc] * (1.f / 32768.f) - mu * mu;
  float rs = rsqrtf(va + 1e-5f);
  float gg = g[oc], bb = b[oc];
  size_t pb = (size_t)blk * 32 * OCH + oc;
  for (int w2 = 0; w2 < 32; ++w2) {
    float v = (float)pre16[pb + (size_t)w2 * OCH] + xt[w2][oc];
    v = (v - mu) * rs * gg + bb;
    xt[w2][oc] = fminf(fmaxf(v, -1.f), 1.f);   // in-place: col oc owned by thread
  }
  __syncthreads();
  for (int k = 0; k < 32; ++k) {
    int oc2 = og * 32 + k;
    out[((size_t)(n * 256 + oc2) * 32 + h) * 32 + w] = xt[w][oc2];
  }
  if (blk == 0 && t == 0) out[8388608] = r0[0] + 8.625f;
}

extern "C" void kernel_launch(void* const* d_in, const int* in_sizes, int n_in,
                              void* d_out, int out_size, void* d_ws, size_t ws_size,
                              hipStream_t stream) {
  const float* x0   = (const float*)d_in[0];
  const float* reg0 = (const float*)d_in[1];
  const float* w1   = (const float*)d_in[2];
  const float* g1   = (const float*)d_in[3];
  const float* b1   = (const float*)d_in[4];
  const float* w2   = (const float*)d_in[5];
  const float* g2   = (const float*)d_in[6];
  const float* b2   = (const float*)d_in[7];

  char* ws = (char*)d_ws;
  u64*   Wbits = (u64*)(ws);                        // 147456 B  [layer][ck][oc]
  u64*   masks = (u64*)(ws + 147456);               // 2592 B
  float* st    = (float*)(ws + 151552);             // 4 KiB
  u64*   Sb    = (u64*)(ws + 155648);               // 1 MiB
  signed char* Bi8 = (signed char*)(ws + 1204224);  // 1179648 B [l][t][o][c]
  signed char* Ai8 = (signed char*)(ws + 2383872) + 32768;  // 8 MiB + 32K guards
  short* v16   = (short*)(ws + 10838016);           // 16 MiB (conv1 out,
                                                    //  then reused for conv2)

  bb_pre    <<<10241, 256, 0, stream>>>(w1, w2, x0, Wbits, Bi8, st, masks,
                                        Sb, Ai8);
  bb_conv   <<<760, 256, GLDS, stream>>>(Ai8, Bi8, Sb, Wbits, masks, v16);
  bb_stats1 <<<256, 256, 0, stream>>>(v16, st);
  bb_xbits2 <<<1024, 256, 0, stream>>>(v16, st, g1, b1, Sb, Ai8);
  bb_conv   <<<760, 256, GLDS, stream>>>(Ai8, Bi8 + 589824, Sb,
                                         Wbits + OCH * NCH, masks, v16);
  bb_stats2t<<<1024, 256, 0, stream>>>(v16, x0, st);
  bb_fint   <<<1024, 256, 0, stream>>>(v16, x0, st, g2, b2, reg0, (float*)d_out);
}

// Round 13
// 257.458 us; speedup vs baseline: 1.2429x; 1.1009x over previous
//
#include <hip/hip_runtime.h>

typedef unsigned long long u64;
typedef __attribute__((ext_vector_type(4)))  int i32x4;
typedef __attribute__((ext_vector_type(16))) int i32x16;

// x [32,256,32,32] f32, w [256,256,3,3] f32; reduction R = 2304 = 36 x 64.
#define NPIX   32768
#define OCH    256
#define NCH    36

// gemm geometry: 128px x 128oc block, 4 waves of 64x64, BK=64, K=36 steps.
#define AROWS  196            // px tile 128 + tap halo (+-33)
#define ALDS   (AROWS * 256)  // 50176 B dynamic LDS (A slab only; B is global->VGPR)

__device__ __forceinline__ void gload16(const void* g, void* l) {
  __builtin_amdgcn_global_load_lds(
      (const __attribute__((address_space(1))) unsigned*)g,
      (__attribute__((address_space(3))) unsigned*)l, 16, 0, 0);
}

// stage 0 (mega-prep, 10241 blocks): all four independent prep passes in one
// dispatch so their latency overlaps on idle CUs.
//   blk 0                : zero stats + boundary masks
//   blk 1..4608          : weight sign bits WbitsT[layer][chunk][oc]
//   blk 4609..9216       : i8 weight operand B3[l][tap][slot][oc][16B]
//                          (slot = cb*4+s for c = cb*64+s*16+j -- makes a
//                          wave's MFMA B-fragment two dense 512-B segments)
//   blk 9217..10240      : x0 sign bitplanes Sb + i8 NHWC operand A
__global__ __launch_bounds__(256) void bb_pre(const float* __restrict__ wa,
                                              const float* __restrict__ wb,
                                              const float* __restrict__ x,
                                              u64* __restrict__ Wbits,
                                              signed char* __restrict__ B,
                                              float* __restrict__ st,
                                              u64* __restrict__ masks,
                                              u64* __restrict__ Sb,
                                              signed char* __restrict__ A) {
  __shared__ float xt[256][33];
  int blk = blockIdx.x, t = threadIdx.x;
  if (blk == 0) {
    for (int i = t; i < 1024; i += 256) st[i] = 0.f;
    for (int id = t; id < 9 * NCH; id += 256) {
      int cls = id / NCH, ck = id % NCH;
      int ch = cls / 3, cw = cls % 3;
      u64 m = 0;
      for (int b = 0; b < 64; ++b) {
        int r = ck * 64 + b, tap = r % 9, kh = tap / 3, kw = tap % 3;
        bool oob = (ch == 0 && kh == 0) || (ch == 2 && kh == 2) ||
                   (cw == 0 && kw == 0) || (cw == 2 && kw == 2);
        if (!oob) m |= (u64)1 << b;
      }
      masks[id] = m;
    }
  } else if (blk <= 4608) {
    int word = (((blk - 1) << 8) + t) >> 6;
    int ln = t & 63;
    const float* src = (word < OCH * NCH) ? wa : wb;
    int r = word % (OCH * NCH);        // r = oc*36 + ck over w[o][2304]
    u64 bits = __ballot(src[(size_t)r * 64 + ln] >= 0.f);
    int l = word / (OCH * NCH);
    int o = r / NCH, ck = r % NCH;
    if (ln == 0) Wbits[(size_t)l * OCH * NCH + (size_t)ck * OCH + o] = bits;
  } else if (blk <= 9216) {
    int tid = ((blk - 4609) << 8) + t;  // 2 * 589824 ids
    int l = tid >= 589824;
    int r = l ? tid - 589824 : tid;
    const float* src = l ? wb : wa;
    float v = src[r];
    int tp = r % 9, oc9 = r / 9;
    int c = oc9 & 255, o = oc9 >> 8;
    int cb = c >> 6, s = (c >> 4) & 3, j = c & 15;
    B[(((size_t)((l * 9 + tp) * 16 + cb * 4 + s)) << 12) + (o << 4) + j] =
        (v >= 0.f) ? 1 : -1;
  } else {
    int bx = blk - 9217;               // 1024 xbits blocks
    int n = bx >> 5, h = bx & 31;
    int w = t & 31, cg = t >> 5;        // 8 c-groups
    for (int k = 0; k < 32; ++k) {
      int c = k * 8 + cg;
      xt[c][w] = x[((size_t)((n * 256 + c) * 32 + h) << 5) + w];
    }
    __syncthreads();
    int ln = t & 63, wv = t >> 6;       // 4 waves = 4 channel-words
    int c2 = wv * 64 + ln;
    for (int w2 = 0; w2 < 32; ++w2) {
      bool s = xt[c2][w2] >= 0.f;
      u64 bits = __ballot(s);
      int px = (n * 32 + h) * 32 + w2;
      A[(size_t)px * 256 + c2] = s ? 1 : -1;
      if (ln == 0) Sb[(size_t)px * 4 + wv] = bits;
    }
  }
}

// stage 1 (merged conv, 760 blocks, dynamic LDS = ALDS):
//   bx 0..511   : interior i8 implicit GEMM, BARRIER-FREE K-loop. A staged
//                 once to LDS (one barrier total); B fragments read directly
//                 global->VGPR from the L2-resident B3 layout -- per step the
//                 B address is one pointer += 16384 with immediate offsets,
//                 so the compiler software-pipelines loads across steps
//                 (round-10's failure was the (256,3) VGPR cap; now (256,2)).
//                 Epilogue stores MASKED to interior (round-11 race lesson).
//   bx 512..759 : boundary pixels, 16 px per block, exact masked path; LDS
//                 carved from the same dynamic buffer (13.6 KB < ALDS).
__global__ __launch_bounds__(256, 2) void bb_conv(const signed char* __restrict__ A,
                                                  const signed char* __restrict__ B,
                                                  const u64* __restrict__ Sb,
                                                  const u64* __restrict__ Wb,
                                                  const u64* __restrict__ masks,
                                                  short* __restrict__ dst) {
  extern __shared__ signed char sm[];
  int bx = blockIdx.x, t = threadIdx.x;
  if (bx < 512) {
    int wv = t >> 6, ln = t & 63;
    int lw = ln & 31, hk = ln >> 5;
    int px0 = (bx >> 1) << 7;
    int oc0 = (bx & 1) << 7;

    // ---- stage A once: rows px0-33 .. px0+162 (196 rows x 256 B) ----
    const signed char* Abase = A + (size_t)(px0 - 33) * 256;
    #pragma unroll
    for (int i = 0; i < 13; ++i) {
      int c = i * 4 + wv;
      if (c < 49) {
        int u = c * 64 + ln;
        int row = u >> 4, p = u & 15;
        gload16(Abase + (size_t)row * 256 + (((p ^ (row & 7)) << 4)),
                &sm[c * 1024]);
      }
    }
    asm volatile("s_waitcnt vmcnt(0)" ::: "memory");
    __builtin_amdgcn_s_barrier();

    int wm = wv >> 1, wn = wv & 1;
    int arow0 = 33 + (wm << 6) + lw;
    // B3 slot = 4*ks + 2*k32 + hk; element (slot, oc) at slot*4096 + oc*16.
    const signed char* Bp = B + (((size_t)(oc0 + (wn << 6) + lw)) << 4)
                              + (hk << 12);
    i32x16 acc00 = {0,0,0,0,0,0,0,0,0,0,0,0,0,0,0,0};
    i32x16 acc01 = acc00, acc10 = acc00, acc11 = acc00;

    #pragma unroll 4
    for (int ks = 0; ks < 36; ++ks) {
      int tp = ks >> 2, cb = ks & 3;
      int dpx = (tp / 3 - 1) * 32 + (tp % 3 - 1);
      int r0 = arow0 + dpx, r1 = r0 + 32;
      #pragma unroll
      for (int k32 = 0; k32 < 2; ++k32) {
        int sa = cb * 4 + k32 * 2 + hk;
        i32x4 a0 = *(const i32x4*)(sm + r0 * 256 + ((sa ^ (r0 & 7)) << 4));
        i32x4 a1 = *(const i32x4*)(sm + r1 * 256 + ((sa ^ (r1 & 7)) << 4));
        i32x4 b0 = *(const i32x4*)(Bp + (k32 << 13));
        i32x4 b1 = *(const i32x4*)(Bp + (k32 << 13) + 512);
        acc00 = __builtin_amdgcn_mfma_i32_32x32x32_i8(a0, b0, acc00, 0, 0, 0);
        acc01 = __builtin_amdgcn_mfma_i32_32x32x32_i8(a0, b1, acc01, 0, 0, 0);
        acc10 = __builtin_amdgcn_mfma_i32_32x32x32_i8(a1, b0, acc10, 0, 0, 0);
        acc11 = __builtin_amdgcn_mfma_i32_32x32x32_i8(a1, b1, acc11, 0, 0, 0);
      }
      Bp += 16384;
    }

    int px0w = px0 + (wm << 6), oc0w = oc0 + (wn << 6);
    int rbase = hk << 2;
    int h0 = (px0w >> 5) & 31, h1 = ((px0w + 32) >> 5) & 31;
    bool i0 = (h0 >= 1) && (h0 <= 30);
    bool i1 = (h1 >= 1) && (h1 <= 30);
    #pragma unroll
    for (int r = 0; r < 16; ++r) {     // C/D: col=lane&31, row=(r&3)+8*(r>>2)+4*hk
      int m = (r & 3) + ((r >> 2) << 3) + rbase;
      bool wok = (m >= 1) && (m <= 30);
      size_t row0 = ((size_t)(px0w + m)) << 8;
      size_t row1 = ((size_t)(px0w + 32 + m)) << 8;
      int v;
      if (i0 && wok) {
        v = acc00[r]; v = v < -254 ? -254 : (v > 254 ? 254 : v);
        dst[row0 + oc0w + lw] = (short)v;
        v = acc01[r]; v = v < -254 ? -254 : (v > 254 ? 254 : v);
        dst[row0 + oc0w + 32 + lw] = (short)v;
      }
      if (i1 && wok) {
        v = acc10[r]; v = v < -254 ? -254 : (v > 254 ? 254 : v);
        dst[row1 + oc0w + lw] = (short)v;
        v = acc11[r]; v = v < -254 ? -254 : (v > 254 ? 254 : v);
        dst[row1 + oc0w + 32 + lw] = (short)v;
      }
    }
    return;
  }

  // ---- boundary path: LDS carved from the dynamic buffer ----
  u64* spread = (u64*)sm;                    // 2048 B
  u64* pw     = spread + 256;                // 16*36 u64 = 4608 B
  u64* mm     = pw + 16 * NCH;               // 4608 B
  int* pm     = (int*)(mm + 16 * NCH);       // 2304 B
  int* pxl    = pm + 16 * NCH;               // 64 B   (total ~13.6 KB < ALDS)
  {
    u64 v = 0;
    for (int k = 0; k < 8; ++k) if (t & (1 << k)) v |= (u64)1 << (9 * k);
    spread[t] = v;
  }
  __syncthreads();
  int bb = bx - 512;
  for (int id = t; id < 16 * NCH; id += 256) {
    int p = id / NCH, ck = id % NCH;
    int gp = bb * 16 + p;
    int n = gp / 124, r = gp % 124;
    int h, w;
    if (r < 32)      { h = 0;      w = r;      }
    else if (r < 64) { h = 31;     w = r - 32; }
    else if (r < 94) { h = r - 63; w = 0;      }
    else             { h = r - 93; w = 31;     }
    int cls = (h == 0 ? 0 : (h == 31 ? 2 : 1)) * 3 + (w == 0 ? 0 : (w == 31 ? 2 : 1));
    if (ck == 0) pxl[p] = ((n * 32 + h) << 5) + w;
    int base9 = ck % 9;
    u64 acc = 0;
    for (int tap = 0; tap < 9; ++tap) {
      int b0 = tap - base9; if (b0 < 0) b0 += 9;
      int nh = h + tap / 3 - 1, nw = w + tap % 3 - 1;
      if ((unsigned)nh <= 31u && (unsigned)nw <= 31u) {
        int run = (b0 == 0) ? 8 : 7;
        int c0 = (ck * 64 + b0) / 9;
        const u64* rp = Sb + ((size_t)((n * 32 + nh) * 32 + nw) << 2);
        int wi = c0 >> 6, sh = c0 & 63;
        u64 v = rp[wi] >> sh;
        if (sh + run > 64) v |= rp[wi + 1] << (64 - sh);
        v &= (run == 8) ? 0xFFull : 0x7Full;
        acc |= spread[(int)v] << b0;
      }
    }
    pw[p * NCH + ck] = acc;
    u64 m = masks[cls * NCH + ck];
    mm[p * NCH + ck] = m;
    pm[p * NCH + ck] = __popcll(m);
  }
  __syncthreads();
  int oc = t;
  int acc[16];
  #pragma unroll
  for (int p = 0; p < 16; ++p) acc[p] = 0;
  for (int i = 0; i < NCH; ++i) {
    u64 wr = Wb[(size_t)i * OCH + oc];
    #pragma unroll
    for (int p = 0; p < 16; ++p) {
      int d = __popcll((pw[p * NCH + i] ^ wr) & mm[p * NCH + i]);
      int ps = pm[p * NCH + i] - 2 * d;
      acc[p] += ps + (ps & 1) * ((ps & 2) - 1);
    }
  }
  #pragma unroll
  for (int p = 0; p < 16; ++p) {
    int v = acc[p];
    v = v < -254 ? -254 : (v > 254 ? 254 : v);
    dst[(size_t)pxl[p] * OCH + oc] = (short)v;
  }
}

// stage 2: BN1 batch stats (integer values -> exact f32 sums).
__global__ void bb_stats1(const short* v16, float* st) {
  int t = threadIdx.x;
  const short* base = v16 + (size_t)blockIdx.x * 128 * OCH;
  int s = 0; float q = 0.f;
  for (int r = 0; r < 128; ++r) {
    int v = base[r * OCH + t];
    s += v; q += (float)(v * v);
  }
  atomicAdd(&st[t], (float)s);
  atomicAdd(&st[256 + t], q);
}

// stage 3: BN1 + hardtanh + sign-pack (hardtanh preserves sign) + i8 NHWC A2.
__global__ void bb_xbits2(const short* v16, const float* st,
                          const float* g, const float* b, u64* Sb,
                          signed char* A) {
  int wave = (blockIdx.x * blockDim.x + threadIdx.x) >> 6;
  int ln = threadIdx.x & 63;
  int wrd = wave & 3, px0 = (wave >> 2) * 32;
  int oc = wrd * 64 + ln;
  float mu = st[oc] * (1.f / 32768.f);
  float va = st[256 + oc] * (1.f / 32768.f) - mu * mu;
  float rs = rsqrtf(va + 1e-5f);
  float gg = g[oc], bb = b[oc];
  for (int j = 0; j < 32; ++j) {
    float bn = ((float)v16[(size_t)(px0 + j) * OCH + oc] - mu) * rs * gg + bb;
    bool s = bn >= 0.f;
    u64 bits = __ballot(s);
    A[(size_t)(px0 + j) * 256 + oc] = s ? 1 : -1;
    if (ln == 0) Sb[(size_t)(px0 + j) * 4 + wrd] = bits;
  }
}

// stage 4: BN2 batch stats of (conv2 + residual). Block = one (n,h) row-tile.
__global__ __launch_bounds__(256) void bb_stats2t(const short* __restrict__ pre16,
                                                  const float* __restrict__ x0,
                                                  float* st) {
  __shared__ float xt[32][257];
  int blk = blockIdx.x;                 // blk = n*32 + h
  int n = blk >> 5, h = blk & 31;
  int t = threadIdx.x;
  int w = t & 31, og = t >> 5;          // 8 oc-groups
  for (int k = 0; k < 32; ++k) {
    int oc = og * 32 + k;
    xt[w][oc] = x0[((size_t)(n * 256 + oc) * 32 + h) * 32 + w];
  }
  __syncthreads();
  int oc = t;
  size_t pb = (size_t)blk * 32 * OCH + oc;
  float s = 0.f, q = 0.f;
  for (int w2 = 0; w2 < 32; ++w2) {
    float v = (float)pre16[pb + (size_t)w2 * OCH] + xt[w2][oc];
    s += v; q += v * v;
  }
  atomicAdd(&st[512 + oc], s);
  atomicAdd(&st[768 + oc], q);
}

// stage 5: BN2 + hardtanh + NCHW store via in-place LDS transpose;
// reg output is data-independent: reg = reg0 + r1 + 2*r2 = reg0 + 8.625.
__global__ __launch_bounds__(256) void bb_fint(const short* __restrict__ pre16,
                                               const float* __restrict__ x0,
                                               const float* st, const float* g,
                                               const float* b, const float* r0,
                                               float* __restrict__ out) {
  __shared__ float xt[32][257];
  int blk = blockIdx.x;
  int n = blk >> 5, h = blk & 31;
  int t = threadIdx.x;
  int w = t & 31, og = t >> 5;
  for (int k = 0; k < 32; ++k) {
    int oc = og * 32 + k;
    xt[w][oc] = x0[((size_t)(n * 256 + oc) * 32 + h) * 32 + w];
  }
  __syncthreads();
  int oc = t;
  float mu = st[512 + oc] * (1.f / 32768.f);
  float va = st[768 + oc] * (1.f / 32768.f) - mu * mu;
  float rs = rsqrtf(va + 1e-5f);
  float gg = g[oc], bb = b[oc];
  size_t pb = (size_t)blk * 32 * OCH + oc;
  for (int w2 = 0; w2 < 32; ++w2) {
    float v = (float)pre16[pb + (size_t)w2 * OCH] + xt[w2][oc];
    v = (v - mu) * rs * gg + bb;
    xt[w2][oc] = fminf(fmaxf(v, -1.f), 1.f);   // in-place: col oc owned by thread
  }
  __syncthreads();
  for (int k = 0; k < 32; ++k) {
    int oc2 = og * 32 + k;
    out[((size_t)(n * 256 + oc2) * 32 + h) * 32 + w] = xt[w][oc2];
  }
  if (blk == 0 && t == 0) out[8388608] = r0[0] + 8.625f;
}

extern "C" void kernel_launch(void* const* d_in, const int* in_sizes, int n_in,
                              void* d_out, int out_size, void* d_ws, size_t ws_size,
                              hipStream_t stream) {
  const float* x0   = (const float*)d_in[0];
  const float* reg0 = (const float*)d_in[1];
  const float* w1   = (const float*)d_in[2];
  const float* g1   = (const float*)d_in[3];
  const float* b1   = (const float*)d_in[4];
  const float* w2   = (const float*)d_in[5];
  const float* g2   = (const float*)d_in[6];
  const float* b2   = (const float*)d_in[7];

  char* ws = (char*)d_ws;
  u64*   Wbits = (u64*)(ws);                        // 147456 B  [layer][ck][oc]
  u64*   masks = (u64*)(ws + 147456);               // 2592 B
  float* st    = (float*)(ws + 151552);             // 4 KiB
  u64*   Sb    = (u64*)(ws + 155648);               // 1 MiB
  signed char* Bi8 = (signed char*)(ws + 1204224);  // 1179648 B  B3 layout
  signed char* Ai8 = (signed char*)(ws + 2383872) + 32768;  // 8 MiB + 32K guards
  short* v16   = (short*)(ws + 10838016);           // 16 MiB (conv1 out,
                                                    //  then reused for conv2)

  bb_pre    <<<10241, 256, 0, stream>>>(w1, w2, x0, Wbits, Bi8, st, masks,
                                        Sb, Ai8);
  bb_conv   <<<760, 256, ALDS, stream>>>(Ai8, Bi8, Sb, Wbits, masks, v16);
  bb_stats1 <<<256, 256, 0, stream>>>(v16, st);
  bb_xbits2 <<<1024, 256, 0, stream>>>(v16, st, g1, b1, Sb, Ai8);
  bb_conv   <<<760, 256, ALDS, stream>>>(Ai8, Bi8 + 589824, Sb,
                                         Wbits + OCH * NCH, masks, v16);
  bb_stats2t<<<1024, 256, 0, stream>>>(v16, x0, st);
  bb_fint   <<<1024, 256, 0, stream>>>(v16, x0, st, g2, b2, reg0, (float*)d_out);
}

// Round 14
// 255.025 us; speedup vs baseline: 1.2548x; 1.0095x over previous
//
#include <hip/hip_runtime.h>

typedef unsigned long long u64;
typedef __attribute__((ext_vector_type(4)))  int i32x4;
typedef __attribute__((ext_vector_type(16))) int i32x16;

// x [32,256,32,32] f32, w [256,256,3,3] f32; reduction R = 2304 = 36 x 64.
#define NPIX   32768
#define OCH    256
#define NCH    36

// gemm geometry: 128px x 128oc block, 4 waves of 64x64, BK=64, K=36 steps.
#define AROWS  196            // px tile 128 + tap halo (+-33)
#define ALDS   (AROWS * 256)  // 50176 B dynamic LDS (A slab only; B is global->VGPR)

__device__ __forceinline__ void gload16(const void* g, void* l) {
  __builtin_amdgcn_global_load_lds(
      (const __attribute__((address_space(1))) unsigned*)g,
      (__attribute__((address_space(3))) unsigned*)l, 16, 0, 0);
}

// stage 0 (mega-prep, 6145 blocks): all four independent prep passes in one
// dispatch so their latency overlaps on idle CUs.
//   blk 0           : zero stats + boundary masks
//   blk 1..4608     : weight sign bits WbitsT[layer][chunk][oc]
//   blk 4609..5120  : i8 weight operand B3[l][tap][slot][oc][16B], one o per
//                     block (o = blk&255, c = t): reads are a contiguous
//                     2304-B span per wave (L1-coalesced), writes land as
//                     dense 16-B chunks per slot-page (L2 merges full lines).
//                     Old tid->r map wrote 1 B/lane scattered across 9 pages
//                     (~64x partial-line write amplification).
//   blk 5121..6144  : x0 sign bitplanes Sb + i8 NHWC operand A
__global__ __launch_bounds__(256) void bb_pre(const float* __restrict__ wa,
                                              const float* __restrict__ wb,
                                              const float* __restrict__ x,
                                              u64* __restrict__ Wbits,
                                              signed char* __restrict__ B,
                                              float* __restrict__ st,
                                              u64* __restrict__ masks,
                                              u64* __restrict__ Sb,
                                              signed char* __restrict__ A) {
  __shared__ float xt[256][33];
  int blk = blockIdx.x, t = threadIdx.x;
  if (blk == 0) {
    for (int i = t; i < 1024; i += 256) st[i] = 0.f;
    for (int id = t; id < 9 * NCH; id += 256) {
      int cls = id / NCH, ck = id % NCH;
      int ch = cls / 3, cw = cls % 3;
      u64 m = 0;
      for (int b = 0; b < 64; ++b) {
        int r = ck * 64 + b, tap = r % 9, kh = tap / 3, kw = tap % 3;
        bool oob = (ch == 0 && kh == 0) || (ch == 2 && kh == 2) ||
                   (cw == 0 && kw == 0) || (cw == 2 && kw == 2);
        if (!oob) m |= (u64)1 << b;
      }
      masks[id] = m;
    }
  } else if (blk <= 4608) {
    int word = (((blk - 1) << 8) + t) >> 6;
    int ln = t & 63;
    const float* src = (word < OCH * NCH) ? wa : wb;
    int r = word % (OCH * NCH);        // r = oc*36 + ck over w[o][2304]
    u64 bits = __ballot(src[(size_t)r * 64 + ln] >= 0.f);
    int l = word / (OCH * NCH);
    int o = r / NCH, ck = r % NCH;
    if (ln == 0) Wbits[(size_t)l * OCH * NCH + (size_t)ck * OCH + o] = bits;
  } else if (blk <= 5120) {
    int q = blk - 4609;                // 512 blocks: l = q>>8, o = q&255
    int l = q >> 8, o = q & 255;
    int c = t;
    const float* src = (l ? wb : wa) + ((size_t)o * 256 + c) * 9;
    int cb = c >> 6, s = (c >> 4) & 3, j = c & 15;
    size_t base = (size_t)(l * 9) << 16;
    #pragma unroll
    for (int tp = 0; tp < 9; ++tp) {
      B[base + (((size_t)(tp * 16 + cb * 4 + s)) << 12) + (o << 4) + j] =
          (src[tp] >= 0.f) ? 1 : -1;
    }
  } else {
    int bx = blk - 5121;               // 1024 xbits blocks
    int n = bx >> 5, h = bx & 31;
    int w = t & 31, cg = t >> 5;        // 8 c-groups
    for (int k = 0; k < 32; ++k) {
      int c = k * 8 + cg;
      xt[c][w] = x[((size_t)((n * 256 + c) * 32 + h) << 5) + w];
    }
    __syncthreads();
    int ln = t & 63, wv = t >> 6;       // 4 waves = 4 channel-words
    int c2 = wv * 64 + ln;
    for (int w2 = 0; w2 < 32; ++w2) {
      bool s = xt[c2][w2] >= 0.f;
      u64 bits = __ballot(s);
      int px = (n * 32 + h) * 32 + w2;
      A[(size_t)px * 256 + c2] = s ? 1 : -1;
      if (ln == 0) Sb[(size_t)px * 4 + wv] = bits;
    }
  }
}

// stage 1 (merged conv, 760 blocks, dynamic LDS = ALDS):
//   bx 0..511   : interior i8 implicit GEMM, BARRIER-FREE K-loop (round-13:
//                 46.6us, MfmaUtil 15.5%). Now __launch_bounds__(256,3):
//                 3 blocks/CU (LDS 3x50176 = 150.5KB < 160KB; regs 124 < 168
//                 cap) -> 12 waves/CU for latency hiding.
//                 Epilogue stores MASKED to interior (round-11 race lesson).
//   bx 512..759 : boundary pixels, 16 px per block, exact masked path; LDS
//                 carved from the same dynamic buffer (13.6 KB < ALDS).
__global__ __launch_bounds__(256, 3) void bb_conv(const signed char* __restrict__ A,
                                                  const signed char* __restrict__ B,
                                                  const u64* __restrict__ Sb,
                                                  const u64* __restrict__ Wb,
                                                  const u64* __restrict__ masks,
                                                  short* __restrict__ dst) {
  extern __shared__ signed char sm[];
  int bx = blockIdx.x, t = threadIdx.x;
  if (bx < 512) {
    int wv = t >> 6, ln = t & 63;
    int lw = ln & 31, hk = ln >> 5;
    int px0 = (bx >> 1) << 7;
    int oc0 = (bx & 1) << 7;

    // ---- stage A once: rows px0-33 .. px0+162 (196 rows x 256 B) ----
    const signed char* Abase = A + (size_t)(px0 - 33) * 256;
    #pragma unroll
    for (int i = 0; i < 13; ++i) {
      int c = i * 4 + wv;
      if (c < 49) {
        int u = c * 64 + ln;
        int row = u >> 4, p = u & 15;
        gload16(Abase + (size_t)row * 256 + (((p ^ (row & 7)) << 4)),
                &sm[c * 1024]);
      }
    }
    asm volatile("s_waitcnt vmcnt(0)" ::: "memory");
    __builtin_amdgcn_s_barrier();

    int wm = wv >> 1, wn = wv & 1;
    int arow0 = 33 + (wm << 6) + lw;
    // B3 slot = 4*ks + 2*k32 + hk; element (slot, oc) at slot*4096 + oc*16.
    const signed char* Bp = B + (((size_t)(oc0 + (wn << 6) + lw)) << 4)
                              + (hk << 12);
    i32x16 acc00 = {0,0,0,0,0,0,0,0,0,0,0,0,0,0,0,0};
    i32x16 acc01 = acc00, acc10 = acc00, acc11 = acc00;

    #pragma unroll 4
    for (int ks = 0; ks < 36; ++ks) {
      int tp = ks >> 2, cb = ks & 3;
      int dpx = (tp / 3 - 1) * 32 + (tp % 3 - 1);
      int r0 = arow0 + dpx, r1 = r0 + 32;
      #pragma unroll
      for (int k32 = 0; k32 < 2; ++k32) {
        int sa = cb * 4 + k32 * 2 + hk;
        i32x4 a0 = *(const i32x4*)(sm + r0 * 256 + ((sa ^ (r0 & 7)) << 4));
        i32x4 a1 = *(const i32x4*)(sm + r1 * 256 + ((sa ^ (r1 & 7)) << 4));
        i32x4 b0 = *(const i32x4*)(Bp + (k32 << 13));
        i32x4 b1 = *(const i32x4*)(Bp + (k32 << 13) + 512);
        acc00 = __builtin_amdgcn_mfma_i32_32x32x32_i8(a0, b0, acc00, 0, 0, 0);
        acc01 = __builtin_amdgcn_mfma_i32_32x32x32_i8(a0, b1, acc01, 0, 0, 0);
        acc10 = __builtin_amdgcn_mfma_i32_32x32x32_i8(a1, b0, acc10, 0, 0, 0);
        acc11 = __builtin_amdgcn_mfma_i32_32x32x32_i8(a1, b1, acc11, 0, 0, 0);
      }
      Bp += 16384;
    }

    int px0w = px0 + (wm << 6), oc0w = oc0 + (wn << 6);
    int rbase = hk << 2;
    int h0 = (px0w >> 5) & 31, h1 = ((px0w + 32) >> 5) & 31;
    bool i0 = (h0 >= 1) && (h0 <= 30);
    bool i1 = (h1 >= 1) && (h1 <= 30);
    #pragma unroll
    for (int r = 0; r < 16; ++r) {     // C/D: col=lane&31, row=(r&3)+8*(r>>2)+4*hk
      int m = (r & 3) + ((r >> 2) << 3) + rbase;
      bool wok = (m >= 1) && (m <= 30);
      size_t row0 = ((size_t)(px0w + m)) << 8;
      size_t row1 = ((size_t)(px0w + 32 + m)) << 8;
      int v;
      if (i0 && wok) {
        v = acc00[r]; v = v < -254 ? -254 : (v > 254 ? 254 : v);
        dst[row0 + oc0w + lw] = (short)v;
        v = acc01[r]; v = v < -254 ? -254 : (v > 254 ? 254 : v);
        dst[row0 + oc0w + 32 + lw] = (short)v;
      }
      if (i1 && wok) {
        v = acc10[r]; v = v < -254 ? -254 : (v > 254 ? 254 : v);
        dst[row1 + oc0w + lw] = (short)v;
        v = acc11[r]; v = v < -254 ? -254 : (v > 254 ? 254 : v);
        dst[row1 + oc0w + 32 + lw] = (short)v;
      }
    }
    return;
  }

  // ---- boundary path: LDS carved from the dynamic buffer ----
  u64* spread = (u64*)sm;                    // 2048 B
  u64* pw     = spread + 256;                // 16*36 u64 = 4608 B
  u64* mm     = pw + 16 * NCH;               // 4608 B
  int* pm     = (int*)(mm + 16 * NCH);       // 2304 B
  int* pxl    = pm + 16 * NCH;               // 64 B   (total ~13.6 KB < ALDS)
  {
    u64 v = 0;
    for (int k = 0; k < 8; ++k) if (t & (1 << k)) v |= (u64)1 << (9 * k);
    spread[t] = v;
  }
  __syncthreads();
  int bb = bx - 512;
  for (int id = t; id < 16 * NCH; id += 256) {
    int p = id / NCH, ck = id % NCH;
    int gp = bb * 16 + p;
    int n = gp / 124, r = gp % 124;
    int h, w;
    if (r < 32)      { h = 0;      w = r;      }
    else if (r < 64) { h = 31;     w = r - 32; }
    else if (r < 94) { h = r - 63; w = 0;      }
    else             { h = r - 93; w = 31;     }
    int cls = (h == 0 ? 0 : (h == 31 ? 2 : 1)) * 3 + (w == 0 ? 0 : (w == 31 ? 2 : 1));
    if (ck == 0) pxl[p] = ((n * 32 + h) << 5) + w;
    int base9 = ck % 9;
    u64 acc = 0;
    for (int tap = 0; tap < 9; ++tap) {
      int b0 = tap - base9; if (b0 < 0) b0 += 9;
      int nh = h + tap / 3 - 1, nw = w + tap % 3 - 1;
      if ((unsigned)nh <= 31u && (unsigned)nw <= 31u) {
        int run = (b0 == 0) ? 8 : 7;
        int c0 = (ck * 64 + b0) / 9;
        const u64* rp = Sb + ((size_t)((n * 32 + nh) * 32 + nw) << 2);
        int wi = c0 >> 6, sh = c0 & 63;
        u64 v = rp[wi] >> sh;
        if (sh + run > 64) v |= rp[wi + 1] << (64 - sh);
        v &= (run == 8) ? 0xFFull : 0x7Full;
        acc |= spread[(int)v] << b0;
      }
    }
    pw[p * NCH + ck] = acc;
    u64 m = masks[cls * NCH + ck];
    mm[p * NCH + ck] = m;
    pm[p * NCH + ck] = __popcll(m);
  }
  __syncthreads();
  int oc = t;
  int acc[16];
  #pragma unroll
  for (int p = 0; p < 16; ++p) acc[p] = 0;
  for (int i = 0; i < NCH; ++i) {
    u64 wr = Wb[(size_t)i * OCH + oc];
    #pragma unroll
    for (int p = 0; p < 16; ++p) {
      int d = __popcll((pw[p * NCH + i] ^ wr) & mm[p * NCH + i]);
      int ps = pm[p * NCH + i] - 2 * d;
      acc[p] += ps + (ps & 1) * ((ps & 2) - 1);
    }
  }
  #pragma unroll
  for (int p = 0; p < 16; ++p) {
    int v = acc[p];
    v = v < -254 ? -254 : (v > 254 ? 254 : v);
    dst[(size_t)pxl[p] * OCH + oc] = (short)v;
  }
}

// stage 2: BN1 batch stats (integer values -> exact f32 sums).
__global__ void bb_stats1(const short* v16, float* st) {
  int t = threadIdx.x;
  const short* base = v16 + (size_t)blockIdx.x * 128 * OCH;
  int s = 0; float q = 0.f;
  for (int r = 0; r < 128; ++r) {
    int v = base[r * OCH + t];
    s += v; q += (float)(v * v);
  }
  atomicAdd(&st[t], (float)s);
  atomicAdd(&st[256 + t], q);
}

// stage 3: BN1 + hardtanh + sign-pack (hardtanh preserves sign) + i8 NHWC A2.
__global__ void bb_xbits2(const short* v16, const float* st,
                          const float* g, const float* b, u64* Sb,
                          signed char* A) {
  int wave = (blockIdx.x * blockDim.x + threadIdx.x) >> 6;
  int ln = threadIdx.x & 63;
  int wrd = wave & 3, px0 = (wave >> 2) * 32;
  int oc = wrd * 64 + ln;
  float mu = st[oc] * (1.f / 32768.f);
  float va = st[256 + oc] * (1.f / 32768.f) - mu * mu;
  float rs = rsqrtf(va + 1e-5f);
  float gg = g[oc], bb = b[oc];
  for (int j = 0; j < 32; ++j) {
    float bn = ((float)v16[(size_t)(px0 + j) * OCH + oc] - mu) * rs * gg + bb;
    bool s = bn >= 0.f;
    u64 bits = __ballot(s);
    A[(size_t)(px0 + j) * 256 + oc] = s ? 1 : -1;
    if (ln == 0) Sb[(size_t)(px0 + j) * 4 + wrd] = bits;
  }
}

// stage 4: BN2 batch stats of (conv2 + residual). Block = one (n,h) row-tile.
__global__ __launch_bounds__(256) void bb_stats2t(const short* __restrict__ pre16,
                                                  const float* __restrict__ x0,
                                                  float* st) {
  __shared__ float xt[32][257];
  int blk = blockIdx.x;                 // blk = n*32 + h
  int n = blk >> 5, h = blk & 31;
  int t = threadIdx.x;
  int w = t & 31, og = t >> 5;          // 8 oc-groups
  for (int k = 0; k < 32; ++k) {
    int oc = og * 32 + k;
    xt[w][oc] = x0[((size_t)(n * 256 + oc) * 32 + h) * 32 + w];
  }
  __syncthreads();
  int oc = t;
  size_t pb = (size_t)blk * 32 * OCH + oc;
  float s = 0.f, q = 0.f;
  for (int w2 = 0; w2 < 32; ++w2) {
    float v = (float)pre16[pb + (size_t)w2 * OCH] + xt[w2][oc];
    s += v; q += v * v;
  }
  atomicAdd(&st[512 + oc], s);
  atomicAdd(&st[768 + oc], q);
}

// stage 5: BN2 + hardtanh + NCHW store via in-place LDS transpose;
// reg output is data-independent: reg = reg0 + r1 + 2*r2 = reg0 + 8.625.
__global__ __launch_bounds__(256) void bb_fint(const short* __restrict__ pre16,
                                               const float* __restrict__ x0,
                                               const float* st, const float* g,
                                               const float* b, const float* r0,
                                               float* __restrict__ out) {
  __shared__ float xt[32][257];
  int blk = blockIdx.x;
  int n = blk >> 5, h = blk & 31;
  int t = threadIdx.x;
  int w = t & 31, og = t >> 5;
  for (int k = 0; k < 32; ++k) {
    int oc = og * 32 + k;
    xt[w][oc] = x0[((size_t)(n * 256 + oc) * 32 + h) * 32 + w];
  }
  __syncthreads();
  int oc = t;
  float mu = st[512 + oc] * (1.f / 32768.f);
  float va = st[768 + oc] * (1.f / 32768.f) - mu * mu;
  float rs = rsqrtf(va + 1e-5f);
  float gg = g[oc], bb = b[oc];
  size_t pb = (size_t)blk * 32 * OCH + oc;
  for (int w2 = 0; w2 < 32; ++w2) {
    float v = (float)pre16[pb + (size_t)w2 * OCH] + xt[w2][oc];
    v = (v - mu) * rs * gg + bb;
    xt[w2][oc] = fminf(fmaxf(v, -1.f), 1.f);   // in-place: col oc owned by thread
  }
  __syncthreads();
  for (int k = 0; k < 32; ++k) {
    int oc2 = og * 32 + k;
    out[((size_t)(n * 256 + oc2) * 32 + h) * 32 + w] = xt[w][oc2];
  }
  if (blk == 0 && t == 0) out[8388608] = r0[0] + 8.625f;
}

extern "C" void kernel_launch(void* const* d_in, const int* in_sizes, int n_in,
                              void* d_out, int out_size, void* d_ws, size_t ws_size,
                              hipStream_t stream) {
  const float* x0   = (const float*)d_in[0];
  const float* reg0 = (const float*)d_in[1];
  const float* w1   = (const float*)d_in[2];
  const float* g1   = (const float*)d_in[3];
  const float* b1   = (const float*)d_in[4];
  const float* w2   = (const float*)d_in[5];
  const float* g2   = (const float*)d_in[6];
  const float* b2   = (const float*)d_in[7];

  char* ws = (char*)d_ws;
  u64*   Wbits = (u64*)(ws);                        // 147456 B  [layer][ck][oc]
  u64*   masks = (u64*)(ws + 147456);               // 2592 B
  float* st    = (float*)(ws + 151552);             // 4 KiB
  u64*   Sb    = (u64*)(ws + 155648);               // 1 MiB
  signed char* Bi8 = (signed char*)(ws + 1204224);  // 1179648 B  B3 layout
  signed char* Ai8 = (signed char*)(ws + 2383872) + 32768;  // 8 MiB + 32K guards
  short* v16   = (short*)(ws + 10838016);           // 16 MiB (conv1 out,
                                                    //  then reused for conv2)

  bb_pre    <<<6145, 256, 0, stream>>>(w1, w2, x0, Wbits, Bi8, st, masks,
                                       Sb, Ai8);
  bb_conv   <<<760, 256, ALDS, stream>>>(Ai8, Bi8, Sb, Wbits, masks, v16);
  bb_stats1 <<<256, 256, 0, stream>>>(v16, st);
  bb_xbits2 <<<1024, 256, 0, stream>>>(v16, st, g1, b1, Sb, Ai8);
  bb_conv   <<<760, 256, ALDS, stream>>>(Ai8, Bi8 + 589824, Sb,
                                         Wbits + OCH * NCH, masks, v16);
  bb_stats2t<<<1024, 256, 0, stream>>>(v16, x0, st);
  bb_fint   <<<1024, 256, 0, stream>>>(v16, x0, st, g2, b2, reg0, (float*)d_out);
}